// Round 17
// baseline (333.285 us; speedup 1.0000x reference)
//
#include <hip/hip_runtime.h>
#include <hip/hip_bf16.h>

// ChebyKAN: y[b,o] = sum_{i,d} T_d(tanh(x[b,i])) * W[i,o,d]
// GEMM M=16384, N=1024, K=9216 with generated A (packed-fp16 Chebyshev recurrence).
// R13: m201-style fine phases: per degree {vmcnt(counted); barrier; stage 1
//      gload_lds; LOADB(next deg, 2nd bf set); REC(next A); setprio MFMA8}.
//      B-reads depth-1 pipelined (compiler emits counted lgkmcnt); stage9
//      spread 1/phase -> uniform vmcnt(7)/vmcnt(11). Breaks the per-SIMD
//      read-burst/MFMA-burst convoy that kept pipes serial (715k sum ~ 670k wall).

#define WSCALE 4096.0f
#define INV_WSCALE (1.0f/4096.0f)

typedef _Float16 f16;
typedef __fp16   hf2  __attribute__((ext_vector_type(2)));
typedef _Float16 f16x8 __attribute__((ext_vector_type(8)));
typedef float    f32x4 __attribute__((ext_vector_type(4)));
typedef float    f32x16 __attribute__((ext_vector_type(16)));

union F16x8u { hf2 h2[4]; f16x8 v8; };

// ---- kernel 1: repack cc [I][O][9] f32 -> wt (R5 conflict-free layout)
__global__ __launch_bounds__(256) void wt_transform(const float* __restrict__ cc,
                                                    f16* __restrict__ wt) {
  int t    = blockIdx.x * 256 + threadIdx.x;   // 294912 threads
  int j4   = t & 127;
  int grp  = t >> 7;
  int ncol = grp & 7;
  int rest = grp >> 3;
  int ic   = rest & 31;
  int d    = rest >> 5;                        // 0..8
  int u    = j4 >> 5;
  int h    = (j4 >> 4) & 1;
  int r    = j4 & 15;
  int rk   = (r >> 1) & 3;
  size_t base = (size_t)(d * 32 + ic) * 32768 + (size_t)ncol * 4096 + (size_t)j4 * 32;
#pragma unroll
  for (int v = 0; v < 4; ++v) {
    int tt = v ^ rk;
    int q  = tt & 1, kl = tt >> 1;
    int o  = ncol * 128 + u * 32 + q * 16 + r;
    int ib = ic * 32 + h * 16 + kl * 8;
    f16x8 val;
#pragma unroll
    for (int e = 0; e < 8; ++e)
      val[e] = (f16)(cc[((size_t)(ib + e) * 1024 + o) * 9 + d] * WSCALE);
    *(f16x8*)(wt + base + v * 8) = val;
  }
}

// ---- kernel 1b: t2 = 2*tanh(x) as f16
__global__ __launch_bounds__(256) void t2_transform(const float* __restrict__ x,
                                                    f16* __restrict__ t2) {
  size_t gid = (size_t)blockIdx.x * 256 + threadIdx.x;   // 2,097,152 threads
  const float* p = x + gid * 8;
  f32x4 a = *(const f32x4*)p;
  f32x4 b = *(const f32x4*)(p + 4);
  float tf[8];
#pragma unroll
  for (int e = 0; e < 8; ++e) {
    float xx = (e < 4) ? a[e] : b[e - 4];
    tf[e] = 1.f - 2.f * __builtin_amdgcn_rcpf(__expf(2.f * xx) + 1.f);
  }
  F16x8u u;
#pragma unroll
  for (int q = 0; q < 4; ++q)
    u.h2[q] = __builtin_amdgcn_cvt_pkrtz(tf[2 * q], tf[2 * q + 1]);
  f16x8 v = u.v8 + u.v8;
  *(f16x8*)(t2 + gid * 8) = v;
}

// ---- kernel 2: fused basis-gen + GEMM, 256x128 tile, 8 waves of 64m x 64n
__global__ __launch_bounds__(512, 2) void cheby_gemm(const f16* __restrict__ t2g,
                                                     const f16* __restrict__ wt,
                                                     float* __restrict__ out) {
  __shared__ f16 bbuf[18][4096];              // 2 sets x 9 degree-bufs x 8KB = 144KB

  const int tid  = threadIdx.x;
  const int wid  = tid >> 6;
  const int lane = tid & 63;
  const int lr   = lane & 31;
  const int lh   = lane >> 5;
  const int wm   = wid >> 1;
  const int wn   = wid & 1;
  const int mrow = blockIdx.x >> 3;
  const int ncol = blockIdx.x & 7;
  const int m0   = mrow * 256 + wm * 64;
  const int n0   = ncol * 128 + wn * 64;
  const int rbase = wn * 2048 + ((lane & 15) * 4 + ((lane >> 4) ^ ((lane >> 1) & 3))) * 8;

  auto stage = [&](int cn, int dn, int buf) {
    const f16* src = wt + (size_t)(dn * 32 + cn) * 32768 + (size_t)ncol * 4096;
    __builtin_amdgcn_global_load_lds(
        (const __attribute__((address_space(1))) unsigned*)(src + tid * 8),
        (__attribute__((address_space(3))) unsigned*)(&bbuf[buf][wid * 512]),
        16, 0, 0);
  };

  f32x16 acc[2][2];
#pragma unroll
  for (int a = 0; a < 2; ++a)
#pragma unroll
    for (int b = 0; b < 2; ++b)
#pragma unroll
      for (int j = 0; j < 16; ++j) acc[a][b][j] = 0.f;

  const f16x8 ones  = {(f16)1,(f16)1,(f16)1,(f16)1,(f16)1,(f16)1,(f16)1,(f16)1};
  const f16x8 half8 = {(f16)0.5f,(f16)0.5f,(f16)0.5f,(f16)0.5f,
                       (f16)0.5f,(f16)0.5f,(f16)0.5f,(f16)0.5f};
  f16x8 t2v[2][2], t2n[2][2];

  auto loadx = [&](int cn) {   // 4 VMEM f16x8 -> t2n
#pragma unroll
    for (int mb = 0; mb < 2; ++mb)
#pragma unroll
      for (int h = 0; h < 2; ++h)
        t2n[mb][h] = *(const f16x8*)(t2g + (size_t)(m0 + mb * 32 + lr) * 1024
                                         + cn * 32 + h * 16 + lh * 8);
  };

#define REC(NEW, S1, S2)                                                       \
  _Pragma("unroll") for (int mb = 0; mb < 2; ++mb)                             \
    _Pragma("unroll") for (int h = 0; h < 2; ++h)                              \
      NEW[mb][h] = __builtin_elementwise_fma(t2v[mb][h], S1[mb][h], -S2[mb][h]);

#define LOADB(BD, SB, DIDX)                                                    \
  {                                                                            \
    const f16* bb = &bbuf[0][0] + (SB) + (DIDX) * 4096 + rbase;                \
    BD[0][0] = *(const f16x8*)&bb[0];    BD[0][1] = *(const f16x8*)&bb[512];   \
    BD[1][0] = *(const f16x8*)&bb[1024]; BD[1][1] = *(const f16x8*)&bb[1536];  \
  }

#define MFMA8(AF, BD)                                                          \
  {                                                                            \
    __builtin_amdgcn_s_setprio(1);                                             \
    _Pragma("unroll") for (int nb = 0; nb < 2; ++nb)                           \
      _Pragma("unroll") for (int mb = 0; mb < 2; ++mb) {                       \
        acc[mb][nb] = __builtin_amdgcn_mfma_f32_32x32x16_f16(AF[mb][0], BD[nb][0], \
                                                             acc[mb][nb], 0, 0, 0); \
        acc[mb][nb] = __builtin_amdgcn_mfma_f32_32x32x16_f16(AF[mb][1], BD[nb][1], \
                                                             acc[mb][nb], 0, 0, 0); \
      }                                                                        \
    __builtin_amdgcn_s_setprio(0);                                             \
  }

#define VMB(N)                                                                 \
  asm volatile("s_waitcnt vmcnt(" #N ")" ::: "memory");                        \
  __builtin_amdgcn_s_barrier();

  // prologue: stage chunk0 set0 (9 VMEM), loadx(0) (4 VMEM)
#pragma unroll
  for (int d = 0; d < 9; ++d) stage(0, d, d);
  loadx(0);

  f16x8 onesA[2][2];
#pragma unroll
  for (int mb = 0; mb < 2; ++mb)
#pragma unroll
    for (int h = 0; h < 2; ++h) onesA[mb][h] = ones;

  f16x8 bfA[2][2], bfB[2][2];
  f16x8 A1[2][2], A2[2][2], A3[2][2], A4[2][2], A5[2][2], A6[2][2], A7[2][2], A8[2][2];

  for (int c = 0; c < 31; ++c) {
    const int sbase = (c & 1) * 36864;        // this chunk's buf set (f16 units)
    const int nbase = (1 - (c & 1)) * 9;      // next chunk's buf index base

    // phase 0 (deg 0): vmcnt(7) proves stage(c,0), loadx(c), stage(c,1)
    VMB(7)
    LOADB(bfA, sbase, 0)
#pragma unroll
    for (int mb = 0; mb < 2; ++mb)
#pragma unroll
      for (int h = 0; h < 2; ++h) {
        t2v[mb][h] = t2n[mb][h];              // adopt chunk-c t2 (before loadx!)
        A1[mb][h]  = t2v[mb][h] * half8;
      }
    stage(c + 1, 0, nbase + 0);
    loadx(c + 1);
    LOADB(bfB, sbase, 1)
    MFMA8(onesA, bfA)

    // phases 1..7: vmcnt(11) proves stage(c,d) and stage(c,d+1)
    VMB(11) stage(c + 1, 1, nbase + 1); LOADB(bfA, sbase, 2) REC(A2, A1, onesA) MFMA8(A1, bfB)
    VMB(11) stage(c + 1, 2, nbase + 2); LOADB(bfB, sbase, 3) REC(A3, A2, A1)    MFMA8(A2, bfA)
    VMB(11) stage(c + 1, 3, nbase + 3); LOADB(bfA, sbase, 4) REC(A4, A3, A2)    MFMA8(A3, bfB)
    VMB(11) stage(c + 1, 4, nbase + 4); LOADB(bfB, sbase, 5) REC(A5, A4, A3)    MFMA8(A4, bfA)
    VMB(11) stage(c + 1, 5, nbase + 5); LOADB(bfA, sbase, 6) REC(A6, A5, A4)    MFMA8(A5, bfB)
    VMB(11) stage(c + 1, 6, nbase + 6); LOADB(bfB, sbase, 7) REC(A7, A6, A5)    MFMA8(A6, bfA)
    VMB(11) stage(c + 1, 7, nbase + 7); LOADB(bfA, sbase, 8) REC(A8, A7, A6)    MFMA8(A7, bfB)

    // phase 8: deg8 reads proven at phase 7; no new reads -> no wait/barrier
    stage(c + 1, 8, nbase + 8);
    MFMA8(A8, bfA)
  }

  // ---- tail chunk c=31 (set 1): all staged; single full drain
  {
    const int sbase = 36864;
    asm volatile("s_waitcnt vmcnt(0)" ::: "memory");
    __builtin_amdgcn_s_barrier();
    LOADB(bfA, sbase, 0)
#pragma unroll
    for (int mb = 0; mb < 2; ++mb)
#pragma unroll
      for (int h = 0; h < 2; ++h) {
        t2v[mb][h] = t2n[mb][h];
        A1[mb][h]  = t2v[mb][h] * half8;
      }
    LOADB(bfB, sbase, 1)
    MFMA8(onesA, bfA)
    LOADB(bfA, sbase, 2) REC(A2, A1, onesA) MFMA8(A1, bfB)
    LOADB(bfB, sbase, 3) REC(A3, A2, A1)    MFMA8(A2, bfA)
    LOADB(bfA, sbase, 4) REC(A4, A3, A2)    MFMA8(A3, bfB)
    LOADB(bfB, sbase, 5) REC(A5, A4, A3)    MFMA8(A4, bfA)
    LOADB(bfA, sbase, 6) REC(A6, A5, A4)    MFMA8(A5, bfB)
    LOADB(bfB, sbase, 7) REC(A7, A6, A5)    MFMA8(A6, bfA)
    LOADB(bfA, sbase, 8) REC(A8, A7, A6)    MFMA8(A7, bfB)
    MFMA8(A8, bfA)
  }
#undef REC
#undef LOADB
#undef MFMA8
#undef VMB

  // epilogue: 32x32 C/D map: col = lane&31, row = (j&3) + 8*(j>>2) + 4*(lane>>5)
#pragma unroll
  for (int mb = 0; mb < 2; ++mb)
#pragma unroll
    for (int nb = 0; nb < 2; ++nb)
#pragma unroll
      for (int j = 0; j < 16; ++j) {
        int row = m0 + mb * 32 + 4 * lh + (j & 3) + 8 * (j >> 2);
        int col = n0 + nb * 32 + lr;
        out[(size_t)row * 1024 + col] = acc[mb][nb][j] * INV_WSCALE;
      }
}

// ---- fallback (ws too small for t2): R12-style in-GEMM tanh, chunk-level sync
__global__ __launch_bounds__(512, 2) void cheby_gemm_fb(const float* __restrict__ x,
                                                        const f16* __restrict__ wt,
                                                        float* __restrict__ out) {
  __shared__ f16 bbuf[18][4096];
  const int tid  = threadIdx.x;
  const int wid  = tid >> 6;
  const int lane = tid & 63;
  const int lr   = lane & 31;
  const int lh   = lane >> 5;
  const int wm   = wid >> 1;
  const int wn   = wid & 1;
  const int mrow = blockIdx.x >> 3;
  const int ncol = blockIdx.x & 7;
  const int m0   = mrow * 256 + wm * 64;
  const int n0   = ncol * 128 + wn * 64;
  const int rbase = wn * 2048 + ((lane & 15) * 4 + ((lane >> 4) ^ ((lane >> 1) & 3))) * 8;

  auto stage = [&](int cn, int dn, int buf) {
    const f16* src = wt + (size_t)(dn * 32 + cn) * 32768 + (size_t)ncol * 4096;
    __builtin_amdgcn_global_load_lds(
        (const __attribute__((address_space(1))) unsigned*)(src + tid * 8),
        (__attribute__((address_space(3))) unsigned*)(&bbuf[buf][wid * 512]),
        16, 0, 0);
  };
  auto stage9 = [&](int cn, int b0) {
#pragma unroll
    for (int d = 0; d < 9; ++d) stage(cn, d, b0 + d);
  };

  f32x16 acc[2][2];
#pragma unroll
  for (int a = 0; a < 2; ++a)
#pragma unroll
    for (int b = 0; b < 2; ++b)
#pragma unroll
      for (int j = 0; j < 16; ++j) acc[a][b][j] = 0.f;

  const f16x8 ones  = {(f16)1,(f16)1,(f16)1,(f16)1,(f16)1,(f16)1,(f16)1,(f16)1};
  const f16x8 half8 = {(f16)0.5f,(f16)0.5f,(f16)0.5f,(f16)0.5f,
                       (f16)0.5f,(f16)0.5f,(f16)0.5f,(f16)0.5f};
  f16x8 t2v[2][2], t2n[2][2];
  f32x4 xf[2][2][2];

  auto loadx = [&](int cn) {
#pragma unroll
    for (int mb = 0; mb < 2; ++mb)
#pragma unroll
      for (int h = 0; h < 2; ++h) {
        const float* p = x + (size_t)(m0 + mb * 32 + lr) * 1024 + cn * 32 + h * 16 + lh * 8;
        xf[mb][h][0] = *(const f32x4*)p;
        xf[mb][h][1] = *(const f32x4*)(p + 4);
      }
  };
  auto dotanh = [&]() {
#pragma unroll
    for (int mb = 0; mb < 2; ++mb)
#pragma unroll
      for (int h = 0; h < 2; ++h) {
        float tf[8];
#pragma unroll
        for (int e = 0; e < 8; ++e) {
          float xx = (e < 4) ? xf[mb][h][0][e] : xf[mb][h][1][e - 4];
          tf[e] = 1.f - 2.f * __builtin_amdgcn_rcpf(__expf(2.f * xx) + 1.f);
        }
        F16x8u u;
#pragma unroll
        for (int q = 0; q < 4; ++q)
          u.h2[q] = __builtin_amdgcn_cvt_pkrtz(tf[2 * q], tf[2 * q + 1]);
        t2n[mb][h] = u.v8 + u.v8;
      }
  };

#define REC(NEW, S1, S2)                                                       \
  _Pragma("unroll") for (int mb = 0; mb < 2; ++mb)                             \
    _Pragma("unroll") for (int h = 0; h < 2; ++h)                              \
      NEW[mb][h] = __builtin_elementwise_fma(t2v[mb][h], S1[mb][h], -S2[mb][h]);
#define CLUSTER(AF, DIDX)                                                      \
  {                                                                            \
    const f16* bb = &bbuf[0][0] + sbase + (DIDX) * 4096 + rbase;               \
    f16x8 bf[2][2];                                                            \
    _Pragma("unroll") for (int nb = 0; nb < 2; ++nb)                           \
      _Pragma("unroll") for (int h = 0; h < 2; ++h)                            \
        bf[nb][h] = *(const f16x8*)&bb[nb * 1024 + h * 512];                   \
    _Pragma("unroll") for (int nb = 0; nb < 2; ++nb)                           \
      _Pragma("unroll") for (int mb = 0; mb < 2; ++mb) {                       \
        acc[mb][nb] = __builtin_amdgcn_mfma_f32_32x32x16_f16(AF[mb][0], bf[nb][0], \
                                                             acc[mb][nb], 0, 0, 0); \
        acc[mb][nb] = __builtin_amdgcn_mfma_f32_32x32x16_f16(AF[mb][1], bf[nb][1], \
                                                             acc[mb][nb], 0, 0, 0); \
      }                                                                        \
  }

  stage9(0, 0);
  loadx(0);
  dotanh();

  f16x8 onesA[2][2];
#pragma unroll
  for (int mb = 0; mb < 2; ++mb)
#pragma unroll
    for (int h = 0; h < 2; ++h) onesA[mb][h] = ones;

  for (int c = 0; c < 32; ++c) {
    const bool lastc = (c == 31);
    const int  sbase = (c & 1) * 36864;
    const int  nbase = (1 - (c & 1)) * 9;

    asm volatile("s_waitcnt vmcnt(8)" ::: "memory");
    __builtin_amdgcn_s_barrier();

    f16x8 A1[2][2], A2[2][2], A3[2][2], A4[2][2], A5[2][2], A6[2][2], A7[2][2], A8[2][2];
#pragma unroll
    for (int mb = 0; mb < 2; ++mb)
#pragma unroll
      for (int h = 0; h < 2; ++h) {
        t2v[mb][h] = t2n[mb][h];
        A1[mb][h]  = t2v[mb][h] * half8;
      }
    if (!lastc) { stage9(c + 1, nbase); loadx(c + 1); }

    CLUSTER(onesA, 0)
    CLUSTER(A1, 1)
    REC(A2, A1, onesA)  CLUSTER(A2, 2)
    REC(A3, A2, A1)     CLUSTER(A3, 3)
    REC(A4, A3, A2)     CLUSTER(A4, 4)
    REC(A5, A4, A3)     CLUSTER(A5, 5)
    REC(A6, A5, A4)     CLUSTER(A6, 6)
    REC(A7, A6, A5)     CLUSTER(A7, 7)
    REC(A8, A7, A6)     CLUSTER(A8, 8)
    if (!lastc) dotanh();
  }
#undef REC
#undef CLUSTER

#pragma unroll
  for (int mb = 0; mb < 2; ++mb)
#pragma unroll
    for (int nb = 0; nb < 2; ++nb)
#pragma unroll
      for (int j = 0; j < 16; ++j) {
        int row = m0 + mb * 32 + 4 * lh + (j & 3) + 8 * (j >> 2);
        int col = n0 + nb * 32 + lr;
        out[(size_t)row * 1024 + col] = acc[mb][nb][j] * INV_WSCALE;
      }
}

extern "C" void kernel_launch(void* const* d_in, const int* in_sizes, int n_in,
                              void* d_out, int out_size, void* d_ws, size_t ws_size,
                              hipStream_t stream) {
  const float* x  = (const float*)d_in[0];
  const float* cc = (const float*)d_in[1];
  f16*   wt  = (f16*)d_ws;                        // 18,874,368 B
  f16*   t2  = (f16*)((char*)d_ws + 18874368);    // 33,554,432 B
  float* out = (float*)d_out;

  hipLaunchKernelGGL(wt_transform, dim3(1152), dim3(256), 0, stream, cc, wt);
  if (ws_size >= 52428800) {
    hipLaunchKernelGGL(t2_transform, dim3(8192), dim3(256), 0, stream, x, t2);
    hipLaunchKernelGGL(cheby_gemm, dim3(512), dim3(512), 0, stream, t2, wt, out);
  } else {
    hipLaunchKernelGGL(cheby_gemm_fb, dim3(512), dim3(512), 0, stream, x, wt, out);
  }
}